// Round 6
// baseline (378.154 us; speedup 1.0000x reference)
//
#include <hip/hip_runtime.h>

#define B_    1024
#define NG_   32
#define F_    16
#define ED_   6
#define EG_   256
#define ET_   262144
#define H1_   5
#define C1_   80
#define HC1_  400
#define C2_   160
#define OBS_  512

#define S1_   408   // LDS bf16 row stride (816B: 16B-aligned, 12-bank row skew)
#define SG_   400   // global bf16 row stride
#define MSG_S 161

typedef unsigned short ushort8v __attribute__((ext_vector_type(8)));

__device__ __forceinline__ float bf2f(unsigned short u) {
  return __uint_as_float(((unsigned int)u) << 16);
}
__device__ __forceinline__ unsigned short f2bf(float f) {
  unsigned int u = __float_as_uint(f);
  u = u + 0x7FFFu + ((u >> 16) & 1u);   // RNE
  return (unsigned short)(u >> 16);
}
__device__ __forceinline__ float dot8(ushort8v hv, float4 wa, float4 wb, float acc) {
  acc = fmaf(bf2f(hv[0]), wa.x, acc);
  acc = fmaf(bf2f(hv[1]), wa.y, acc);
  acc = fmaf(bf2f(hv[2]), wa.z, acc);
  acc = fmaf(bf2f(hv[3]), wa.w, acc);
  acc = fmaf(bf2f(hv[4]), wb.x, acc);
  acc = fmaf(bf2f(hv[5]), wb.y, acc);
  acc = fmaf(bf2f(hv[6]), wb.z, acc);
  acc = fmaf(bf2f(hv[7]), wb.w, acc);
  return acc;
}

// ---------------------------------------------------------------------------
// K1: node transforms (waves 0-6) + bucket build (wave 7). One block/graph.
// Writes xl, xr (bf16 global, stride 400), eorder/bstart (global).
// ---------------------------------------------------------------------------
__global__ __launch_bounds__(512, 2)
void k1_transform_bucket(
    const float* __restrict__ x, const int* __restrict__ eidx,
    const float* __restrict__ Wl1, const float* __restrict__ bl1,
    const float* __restrict__ Wr1, const float* __restrict__ br1,
    unsigned short* __restrict__ xlg, unsigned short* __restrict__ xrg,
    int* __restrict__ eorder_g, int* __restrict__ bstart_g)
{
  __shared__ float xloc[NG_ * F_];
  __shared__ int   edst[EG_];
  const int b = blockIdx.x, tid = threadIdx.x;
  const int n0 = b * NG_, eb = b * EG_;

  if (tid < EG_) edst[tid] = eidx[ET_ + eb + tid] - n0;
  xloc[tid] = x[n0 * F_ + tid];            // NG_*F_ == 512 == blockDim
  __syncthreads();

  if (tid < 448) {
    for (int t = 0; t < 2; ++t) {
      const int ch = tid + t * 448;
      if (ch >= 800) break;
      const bool isL = (ch < 400);
      const int  c   = isL ? ch : ch - 400;
      const float* Wp = (isL ? Wl1 : Wr1) + c * F_;
      const float bias = isL ? bl1[c] : br1[c];
      unsigned short* dst = (isL ? xlg : xrg) + n0 * SG_ + c;
      float w[16];
#pragma unroll
      for (int qk = 0; qk < 4; ++qk) {
        float4 v = *(const float4*)(Wp + qk * 4);
        w[qk*4+0] = v.x; w[qk*4+1] = v.y; w[qk*4+2] = v.z; w[qk*4+3] = v.w;
      }
      for (int n = 0; n < NG_; n += 2) {
        const float* xa = &xloc[n * F_];
        float accA = bias, accB = bias;
#pragma unroll
        for (int qk = 0; qk < 4; ++qk) {
          float4 a  = *(const float4*)(xa + qk * 4);
          float4 bv = *(const float4*)(xa + F_ + qk * 4);
          accA = fmaf(a.x,  w[qk*4+0], accA); accA = fmaf(a.y,  w[qk*4+1], accA);
          accA = fmaf(a.z,  w[qk*4+2], accA); accA = fmaf(a.w,  w[qk*4+3], accA);
          accB = fmaf(bv.x, w[qk*4+0], accB); accB = fmaf(bv.y, w[qk*4+1], accB);
          accB = fmaf(bv.z, w[qk*4+2], accB); accB = fmaf(bv.w, w[qk*4+3], accB);
        }
        dst[n * SG_]       = f2bf(accA);
        dst[(n + 1) * SG_] = f2bf(accB);
      }
    }
  } else {
    // wave 7: deterministic counting sort of edges by dst
    const int lane = tid & 63;
    const int d    = lane & 31;
    const int half = lane >> 5;
    int cnt = 0;
    const int4* ed4 = (const int4*)edst;
    for (int i = 0; i < 32; ++i) {
      int4 v = ed4[half * 32 + i];
      cnt += (v.x == d) + (v.y == d) + (v.z == d) + (v.w == d);
    }
    const int cnt_lo = __shfl(cnt, d);
    const int total  = cnt + __shfl_xor(cnt, 32);
    int pre = total;
#pragma unroll
    for (int off = 1; off < 32; off <<= 1) {
      int tt = __shfl(pre, lane - off);
      if (d >= off) pre += tt;
    }
    const int start = pre - total;
    if (lane < 32) {
      bstart_g[b * 33 + d] = start;
      if (d == 31) bstart_g[b * 33 + 32] = pre;
    }
    int p = start + (half ? cnt_lo : 0);
    for (int i = 0; i < 32; ++i) {
      int4 v = ed4[half * 32 + i];
      const int e = half * 128 + i * 4;
      if (v.x == d) eorder_g[eb + p++] = e;
      if (v.y == d) eorder_g[eb + p++] = e + 1;
      if (v.z == d) eorder_g[eb + p++] = e + 2;
      if (v.w == d) eorder_g[eb + p++] = e + 3;
    }
  }
}

// ---------------------------------------------------------------------------
// K2: edge scores + segment softmax + aggregation. One block/graph.
// Stages xl/xr to LDS; writes h (bf16) into the xr buffer (rows are
// graph-private, xr global only read during staging).
// ---------------------------------------------------------------------------
__global__ __launch_bounds__(512, 2)
void k2_scores_aggregate(
    const unsigned short* __restrict__ xlg, const unsigned short* __restrict__ xrg,
    const int* __restrict__ eidx, const float* __restrict__ eattr,
    const float* __restrict__ We1, const float* __restrict__ att1,
    const float* __restrict__ bc1,
    const int* __restrict__ eorder_g, const int* __restrict__ bstart_g,
    unsigned short* __restrict__ hg)
{
  __shared__ __align__(16) unsigned short xl[NG_ * S1_];
  __shared__ __align__(16) unsigned short xr[NG_ * S1_];
  __shared__ float sc0[EG_ * H1_];
  __shared__ float sc1[EG_ * H1_];
  __shared__ float ea[EG_ * ED_];
  __shared__ int   esrc[EG_], edst[EG_], eorder[EG_];
  __shared__ int   bstart[NG_ + 1];
  __shared__ float deninv[NG_ * H1_];

  const int b = blockIdx.x, tid = threadIdx.x;
  const int n0 = b * NG_, eb = b * EG_;

  // stage xl, xr rows (coalesced 16B chunks), edge data
  for (int i = tid; i < 3200; i += 512) {
    const bool isR = (i >= 1600);
    const int idx = isR ? i - 1600 : i;
    const int n = idx / 50, c8 = idx - n * 50;
    const ushort8v v = *(const ushort8v*)&(isR ? xrg : xlg)[(n0 + n) * SG_ + c8 * 8];
    *(ushort8v*)&(isR ? xr : xl)[n * S1_ + c8 * 8] = v;
  }
  if (tid < EG_) {
    esrc[tid]   = eidx[eb + tid] - n0;
    edst[tid]   = eidx[ET_ + eb + tid] - n0;
    eorder[tid] = eorder_g[eb + tid];
  }
  for (int i = tid; i < EG_ * ED_; i += 512) ea[i] = eattr[eb * ED_ + i];
  if (tid < NG_ + 1) bstart[tid] = bstart_g[b * 33 + tid];
  __syncthreads();

  // P3: edge scores (edge x head-half; s wave-uniform -> s_load weights)
  {
    const int e = tid & 255;
    const int s = __builtin_amdgcn_readfirstlane((int)(tid >> 8) & 1);
    float* const scp = s ? sc1 : sc0;
    const int sl = esrc[e], dl = edst[e];
    const float e0 = ea[e*ED_+0], e1 = ea[e*ED_+1], e2 = ea[e*ED_+2];
    const float e3 = ea[e*ED_+3], e4 = ea[e*ED_+4], e5 = ea[e*ED_+5];
    const unsigned short* xlrow = &xl[sl * S1_ + s * 40];
    const unsigned short* xrrow = &xr[dl * S1_ + s * 40];
#pragma unroll
    for (int h = 0; h < H1_; ++h) {
      float sh = 0.f;
#pragma unroll
      for (int co = 0; co < 5; ++co) {
        const int coff  = h * C1_ + co * 8;
        const int cbase = coff + s * 40;
        ushort8v av = *(const ushort8v*)(xlrow + coff);
        ushort8v rv = *(const ushort8v*)(xrrow + coff);
#pragma unroll
        for (int u = 0; u < 8; ++u) {
          const float* wv6 = &We1[(cbase + u) * ED_];
          float t0 = fmaf(wv6[1], e1, wv6[0] * e0);
          float t1 = fmaf(wv6[3], e3, wv6[2] * e2);
          float t2 = fmaf(wv6[5], e5, wv6[4] * e4);
          float p = (bf2f(av[u]) + bf2f(rv[u])) + (t0 + (t1 + t2));
          p = fmaxf(p, 0.2f * p);
          sh = fmaf(p, att1[cbase + u], sh);
        }
      }
      scp[e * H1_ + h] = sh;
    }
  }
  __syncthreads();

  // P5: segment softmax (exp into sc0, 1/den into deninv)
  if (tid < NG_ * H1_) {
    const int d = tid & 31, h = tid >> 5;
    const int s0 = bstart[d], s1 = bstart[d + 1];
    float m = -INFINITY;
    for (int k = s0; k < s1; ++k) {
      const int e5i = eorder[k] * H1_ + h;
      m = fmaxf(m, sc0[e5i] + sc1[e5i]);
    }
    float den = 0.f;
    for (int k = s0; k < s1; ++k) {
      const int e5i = eorder[k] * H1_ + h;
      float t = expf(sc0[e5i] + sc1[e5i] - m);
      den += t;
      sc0[e5i] = t;
    }
    deninv[tid] = 1.f / (den + 1e-16f);
  }
  __syncthreads();

  // P6: aggregation -> h written straight to global (coalesced 16B stores)
  for (int idx = tid; idx < NG_ * 50; idx += 512) {
    const int d  = idx / 50;
    const int co = idx - d * 50;
    const int c  = co * 8;
    const int h  = co / 10;
    const int s0 = bstart[d], s1 = bstart[d + 1];
    float acc[8] = {0.f,0.f,0.f,0.f,0.f,0.f,0.f,0.f};
    for (int k = s0; k < s1; ++k) {
      const int e = eorder[k];
      const float al = sc0[e * H1_ + h];
      ushort8v xv = *(const ushort8v*)(&xl[esrc[e] * S1_ + c]);
#pragma unroll
      for (int u = 0; u < 8; ++u) acc[u] = fmaf(al, bf2f(xv[u]), acc[u]);
    }
    const float inv = deninv[h * 32 + d];
    ushort8v hv;
#pragma unroll
    for (int u = 0; u < 8; ++u)
      hv[u] = f2bf(fmaxf(fmaf(acc[u], inv, bc1[c + u]), 0.f));
    *(ushort8v*)&hg[(n0 + d) * SG_ + c] = hv;
  }
}

// ---------------------------------------------------------------------------
// K3: layer-2 at the ego node only. One block/graph; h rows staged to LDS.
// ---------------------------------------------------------------------------
__global__ __launch_bounds__(512, 2)
void k3_ego_layer2(
    const int* __restrict__ eidx, const float* __restrict__ eattr,
    const unsigned short* __restrict__ hg,
    const float* __restrict__ Wl2, const float* __restrict__ bl2,
    const float* __restrict__ Wr2, const float* __restrict__ br2,
    const float* __restrict__ We2, const float* __restrict__ att2,
    const float* __restrict__ bc2,
    const int* __restrict__ eorder_g, const int* __restrict__ bstart_g,
    float* __restrict__ egoH)
{
  __shared__ __align__(16) unsigned short hrows[33 * S1_];  // rows 0..31: group srcs; 32: ego
  __shared__ float msgAll[32 * MSG_S];
  __shared__ float out2[C2_], xr2v[C2_], xr2vB[C2_];
  __shared__ float sArr[32], wArr[32];
  __shared__ int   jsrc[32], jeid[32];
  __shared__ float mrun_s, denrun_s, scale_s;
  __shared__ int   sNE;

  const int b = blockIdx.x, tid = threadIdx.x;
  const int n0 = b * NG_, eb = b * EG_;

  if (tid == 0) { sNE = bstart_g[b * 33 + 1]; mrun_s = -INFINITY; denrun_s = 0.f; scale_s = 0.f; }
  if (tid < 50) *(ushort8v*)&hrows[32 * S1_ + tid * 8] =
                *(const ushort8v*)&hg[n0 * SG_ + tid * 8];       // ego row
  if (tid < C2_) out2[tid] = 0.f;
  __syncthreads();

  const int nE = sNE;
  const int cc = (tid < 320) ? (tid % 160) : 0;
  const int q  = (tid < 320) ? (tid / 160) : 0;

  // xr2v = Wr2 @ h[ego] + br2 (k-split over q)
  float myXr = 0.f;
  if (tid < 320) {
    const float* wr = &Wr2[cc * HC1_ + q * 200];
    const unsigned short* hr = &hrows[32 * S1_ + q * 200];
    float a0 = 0.f, a1 = 0.f;
#pragma unroll 5
    for (int kk = 0; kk < 25; ++kk) {
      const int k = kk * 8;
      ushort8v hv = *(const ushort8v*)(hr + k);
      float4 wa = *(const float4*)(wr + k);
      float4 wb = *(const float4*)(wr + k + 4);
      if (kk & 1) a1 = dot8(hv, wa, wb, a1); else a0 = dot8(hv, wa, wb, a0);
    }
    const float a = a0 + a1;
    if (q == 1) xr2vB[cc] = a; else myXr = a;
  }
  __syncthreads();
  if (tid < C2_) xr2v[tid] = myXr + xr2vB[tid] + br2[tid];

  for (int g0 = 0; g0 < nE; g0 += 32) {
    const int ng = min(32, nE - g0);
    if (tid < ng) {
      const int e = eorder_g[eb + g0 + tid];
      jeid[tid] = e;
      jsrc[tid] = eidx[eb + e] - n0;
    }
    __syncthreads();
    for (int i = tid; i < ng * 50; i += 512) {
      const int r = i / 50, c8 = i - r * 50;
      *(ushort8v*)&hrows[r * S1_ + c8 * 8] =
          *(const ushort8v*)&hg[(n0 + jsrc[r]) * SG_ + c8 * 8];
    }
    __syncthreads();

    // messages: thread=(cc, j-parity q), 4 j-chains per weight-row stream
    for (int jb = 0; jb < ng; jb += 8) {
      const int jn = min(8, ng - jb);
      if (tid < 320) {
        const int nj = (jn + 1 - q) >> 1;
        const float* wl = &Wl2[cc * HC1_];
        const float blv = bl2[cc];
        if (nj == 4) {
          const unsigned short* r0 = &hrows[(jb + q + 0) * S1_];
          const unsigned short* r1 = &hrows[(jb + q + 2) * S1_];
          const unsigned short* r2 = &hrows[(jb + q + 4) * S1_];
          const unsigned short* r3 = &hrows[(jb + q + 6) * S1_];
          float a0 = 0.f, a1 = 0.f, a2 = 0.f, a3 = 0.f;
#pragma unroll 2
          for (int kk = 0; kk < 50; ++kk) {
            const int k = kk * 8;
            float4 wa = *(const float4*)(wl + k);
            float4 wb = *(const float4*)(wl + k + 4);
            a0 = dot8(*(const ushort8v*)(r0 + k), wa, wb, a0);
            a1 = dot8(*(const ushort8v*)(r1 + k), wa, wb, a1);
            a2 = dot8(*(const ushort8v*)(r2 + k), wa, wb, a2);
            a3 = dot8(*(const ushort8v*)(r3 + k), wa, wb, a3);
          }
          msgAll[(jb + q + 0) * MSG_S + cc] = a0 + blv;
          msgAll[(jb + q + 2) * MSG_S + cc] = a1 + blv;
          msgAll[(jb + q + 4) * MSG_S + cc] = a2 + blv;
          msgAll[(jb + q + 6) * MSG_S + cc] = a3 + blv;
        } else {
          for (int i = 0; i < nj; ++i) {
            const int j = jb + q + 2 * i;
            const unsigned short* r = &hrows[j * S1_];
            float a0 = 0.f, a1 = 0.f;
#pragma unroll 2
            for (int kk = 0; kk < 50; ++kk) {
              const int k = kk * 8;
              float4 wa = *(const float4*)(wl + k);
              float4 wb = *(const float4*)(wl + k + 4);
              if (kk & 1) a1 = dot8(*(const ushort8v*)(r + k), wa, wb, a1);
              else        a0 = dot8(*(const ushort8v*)(r + k), wa, wb, a0);
            }
            msgAll[j * MSG_S + cc] = a0 + a1 + blv;
          }
        }
      }
    }
    __syncthreads();

    // scores: 8 lanes/edge, shfl reduce; eattr via broadcast global loads
    if (tid < 256) {
      const int j  = tid >> 3;
      const int q8 = tid & 7;
      float s = 0.f;
      if (j < ng) {
        const float* eap = &eattr[(eb + jeid[j]) * ED_];
        const float e0 = eap[0], e1 = eap[1], e2 = eap[2];
        const float e3 = eap[3], e4 = eap[4], e5 = eap[5];
        const float* mrow = &msgAll[j * MSG_S];
        for (int i = 0; i < 20; ++i) {
          const int c2 = q8 * 20 + i;
          const float* wv6 = &We2[c2 * ED_];
          float t0 = fmaf(wv6[1], e1, wv6[0] * e0);
          float t1 = fmaf(wv6[3], e3, wv6[2] * e2);
          float t2 = fmaf(wv6[5], e5, wv6[4] * e4);
          float p = mrow[c2] + xr2v[c2] + (t0 + (t1 + t2));
          p = fmaxf(p, 0.2f * p);
          s = fmaf(p, att2[c2], s);
        }
      }
      s += __shfl_xor(s, 1); s += __shfl_xor(s, 2); s += __shfl_xor(s, 4);
      if (q8 == 0 && j < ng) sArr[j] = s;
    }
    __syncthreads();

    // online softmax merge (wave 0)
    if (tid < 64) {
      const int j = tid & 31;
      float s = (j < ng) ? sArr[j] : -INFINITY;
      float mg = s;
      mg = fmaxf(mg, __shfl_xor(mg, 1));
      mg = fmaxf(mg, __shfl_xor(mg, 2));
      mg = fmaxf(mg, __shfl_xor(mg, 4));
      mg = fmaxf(mg, __shfl_xor(mg, 8));
      mg = fmaxf(mg, __shfl_xor(mg, 16));
      const float mold = mrun_s;
      const float mnew = fmaxf(mold, mg);
      float w = (j < ng) ? expf(s - mnew) : 0.f;
      float dg = w;
      dg += __shfl_xor(dg, 1); dg += __shfl_xor(dg, 2); dg += __shfl_xor(dg, 4);
      dg += __shfl_xor(dg, 8); dg += __shfl_xor(dg, 16);
      if (tid < 32 && j < ng) wArr[j] = w;
      if (tid == 0) {
        const float scl = expf(mold - mnew);
        scale_s  = scl;
        denrun_s = denrun_s * scl + dg;
        mrun_s   = mnew;
      }
    }
    __syncthreads();

    if (tid < C2_) {
      float o = out2[tid] * scale_s;
      for (int j = 0; j < ng; ++j) o = fmaf(wArr[j], msgAll[j * MSG_S + tid], o);
      out2[tid] = o;
    }
    __syncthreads();
  }

  if (tid < C2_) {
    const float v = out2[tid] / (denrun_s + 1e-16f) + bc2[tid];
    egoH[b * C2_ + tid] = fmaxf(v, 0.f);
  }
}

// ---------------------------------------------------------------------------
// K4: dense head + MLP (unchanged from r5). 256 blocks x 512 threads.
// ---------------------------------------------------------------------------
__global__ __launch_bounds__(512, 2)
void mlp_head_kernel(
    const float* __restrict__ egoH,
    const float* __restrict__ Wd1, const float* __restrict__ bd1,
    const float* __restrict__ Wd2, const float* __restrict__ bd2,
    const float* __restrict__ Wf1, const float* __restrict__ bf1,
    const float* __restrict__ Wf2, const float* __restrict__ bf2,
    const float* __restrict__ Wm,  const float* __restrict__ bm,
    const float* __restrict__ Ws,  const float* __restrict__ bs,
    float* __restrict__ out)
{
  __shared__ float hE[4 * C2_];
  __shared__ float t1[4 * NG_];
  __shared__ float dbuf[4 * OBS_];
  __shared__ float f1b[4 * 256];
  __shared__ float f2b[4 * 256];

  const int g0  = blockIdx.x * 4;
  const int tid = threadIdx.x;

  for (int i = tid; i < 4 * C2_; i += 512) hE[i] = egoH[g0 * C2_ + i];
  __syncthreads();

  if (tid < 4 * NG_) {
    const int g = tid >> 5, o = tid & 31;
    float acc = bd1[o];
    const float* w  = &Wd1[o * C2_];
    const float* hp = &hE[g * C2_];
    for (int k = 0; k < C2_; k += 4) {
      float4 hv = *(const float4*)(hp + k);
      float4 wv = *(const float4*)(w + k);
      acc = fmaf(hv.x, wv.x, acc); acc = fmaf(hv.y, wv.y, acc);
      acc = fmaf(hv.z, wv.z, acc); acc = fmaf(hv.w, wv.w, acc);
    }
    t1[tid] = acc;
  }
  __syncthreads();

  for (int idx = tid; idx < 4 * OBS_; idx += 512) {
    const int g = idx >> 9, o = idx & 511;
    float acc = bd2[o];
    const float* w  = &Wd2[o * NG_];
    const float* tp = &t1[g * NG_];
#pragma unroll
    for (int k = 0; k < NG_; k += 4) {
      float4 tv = *(const float4*)(tp + k);
      float4 wv = *(const float4*)(w + k);
      acc = fmaf(tv.x, wv.x, acc); acc = fmaf(tv.y, wv.y, acc);
      acc = fmaf(tv.z, wv.z, acc); acc = fmaf(tv.w, wv.w, acc);
    }
    dbuf[idx] = tanhf(acc);
  }
  __syncthreads();

  {
    const int o = tid & 255, gg = tid >> 8;
    const float* w  = &Wf1[o * OBS_];
    const float* dA = &dbuf[(gg * 2 + 0) * OBS_];
    const float* dB = &dbuf[(gg * 2 + 1) * OBS_];
    float a0 = bf1[o], a1 = a0;
#pragma unroll 2
    for (int k = 0; k < OBS_; k += 4) {
      float4 wv = *(const float4*)(w + k);
      float4 xA = *(const float4*)(dA + k);
      float4 xB = *(const float4*)(dB + k);
      a0 = fmaf(xA.x, wv.x, a0); a0 = fmaf(xA.y, wv.y, a0);
      a0 = fmaf(xA.z, wv.z, a0); a0 = fmaf(xA.w, wv.w, a0);
      a1 = fmaf(xB.x, wv.x, a1); a1 = fmaf(xB.y, wv.y, a1);
      a1 = fmaf(xB.z, wv.z, a1); a1 = fmaf(xB.w, wv.w, a1);
    }
    f1b[(gg * 2 + 0) * 256 + o] = fmaxf(a0, 0.f);
    f1b[(gg * 2 + 1) * 256 + o] = fmaxf(a1, 0.f);
  }
  __syncthreads();

  {
    const int o = tid & 255, gg = tid >> 8;
    const float* w  = &Wf2[o * 256];
    const float* dA = &f1b[(gg * 2 + 0) * 256];
    const float* dB = &f1b[(gg * 2 + 1) * 256];
    float a0 = bf2[o], a1 = a0;
#pragma unroll 2
    for (int k = 0; k < 256; k += 4) {
      float4 wv = *(const float4*)(w + k);
      float4 xA = *(const float4*)(dA + k);
      float4 xB = *(const float4*)(dB + k);
      a0 = fmaf(xA.x, wv.x, a0); a0 = fmaf(xA.y, wv.y, a0);
      a0 = fmaf(xA.z, wv.z, a0); a0 = fmaf(xA.w, wv.w, a0);
      a1 = fmaf(xB.x, wv.x, a1); a1 = fmaf(xB.y, wv.y, a1);
      a1 = fmaf(xB.z, wv.z, a1); a1 = fmaf(xB.w, wv.w, a1);
    }
    f2b[(gg * 2 + 0) * 256 + o] = fmaxf(a0, 0.f);
    f2b[(gg * 2 + 1) * 256 + o] = fmaxf(a1, 0.f);
  }
  __syncthreads();

  if (tid < 16) {
    const int g  = tid >> 2;
    const int a  = (tid >> 1) & 1;
    const int hm = tid & 1;
    const float* fp = &f2b[g * 256];
    const float* w  = hm ? &Ws[a * 256] : &Wm[a * 256];
    float acc = hm ? bs[a] : bm[a];
    for (int k = 0; k < 256; ++k) acc = fmaf(fp[k], w[k], acc);
    if (hm == 0) out[(g0 + g) * 2 + a] = acc;
    else         out[2048 + (g0 + g) * 2 + a] = -5.0f + 3.5f * (tanhf(acc) + 1.0f);
  }
}

extern "C" void kernel_launch(void* const* d_in, const int* in_sizes, int n_in,
                              void* d_out, int out_size, void* d_ws, size_t ws_size,
                              hipStream_t stream) {
  const float* x     = (const float*)d_in[0];
  const int*   eidx  = (const int*)d_in[1];
  const float* eattr = (const float*)d_in[2];
  const float* Wl1 = (const float*)d_in[3];  const float* bl1 = (const float*)d_in[4];
  const float* Wr1 = (const float*)d_in[5];  const float* br1 = (const float*)d_in[6];
  const float* We1 = (const float*)d_in[7];  const float* att1= (const float*)d_in[8];
  const float* bc1 = (const float*)d_in[9];
  const float* Wl2 = (const float*)d_in[10]; const float* bl2 = (const float*)d_in[11];
  const float* Wr2 = (const float*)d_in[12]; const float* br2 = (const float*)d_in[13];
  const float* We2 = (const float*)d_in[14]; const float* att2= (const float*)d_in[15];
  const float* bc2 = (const float*)d_in[16];
  const float* Wd1 = (const float*)d_in[17]; const float* bd1 = (const float*)d_in[18];
  const float* Wd2 = (const float*)d_in[19]; const float* bd2 = (const float*)d_in[20];
  const float* Wf1 = (const float*)d_in[21]; const float* bf1 = (const float*)d_in[22];
  const float* Wf2 = (const float*)d_in[23]; const float* bf2 = (const float*)d_in[24];
  const float* Wm  = (const float*)d_in[25]; const float* bm  = (const float*)d_in[26];
  const float* Ws  = (const float*)d_in[27]; const float* bs  = (const float*)d_in[28];

  // workspace layout (~54.3 MB)
  unsigned short* xlg = (unsigned short*)d_ws;          // [32768][400] bf16 = 26.2 MB
  unsigned short* hg  = xlg + 32768 * SG_;              // xr, then h     = 26.2 MB
  int* eorder_g = (int*)(hg + 32768 * SG_);             // 1.05 MB
  int* bstart_g = eorder_g + ET_;                       // 132 KB
  float* egoH   = (float*)(bstart_g + B_ * 33);         // 640 KB

  k1_transform_bucket<<<B_, 512, 0, stream>>>(
      x, eidx, Wl1, bl1, Wr1, br1, xlg, hg, eorder_g, bstart_g);

  k2_scores_aggregate<<<B_, 512, 0, stream>>>(
      xlg, hg, eidx, eattr, We1, att1, bc1, eorder_g, bstart_g, hg);

  k3_ego_layer2<<<B_, 512, 0, stream>>>(
      eidx, eattr, hg, Wl2, bl2, Wr2, br2, We2, att2, bc2,
      eorder_g, bstart_g, egoH);

  mlp_head_kernel<<<B_ / 4, 512, 0, stream>>>(
      egoH, Wd1, bd1, Wd2, bd2, Wf1, bf1, Wf2, bf2, Wm, bm, Ws, bs,
      (float*)d_out);
}